// Round 7
// baseline (209.210 us; speedup 1.0000x reference)
//
#include <hip/hip_runtime.h>
#include <math.h>

#define N_NODES 40000
#define N_EDGES 640000
#define D 128
#define H 8
#define C 16
#define NB_SCAN 157  // ceil(40000/256)
#define NB_GEMM 313  // ceil(40000/128)
#define KP 136       // padded LDS k-stride (bf16 elems): 272 B = 17*16, frag reads stay 16B-aligned

typedef __attribute__((ext_vector_type(8))) short short8;   // 8 bf16 (4 VGPRs)
typedef __attribute__((ext_vector_type(4))) float floatx4;  // MFMA C/D

// ws layout (float offsets):
//  xh   : 0          .. 2,560,000   (N*128 bf16 stored as ushort)
//  al   : 5,120,000  .. 5,440,000   (N*8)
//  ar   : 5,440,000  .. 5,760,000   (N*8)
//  plg  : 5,760,000  .. 10,880,000  (E*8, dst-sorted logits)
//  psrc : 10,880,000 .. 11,520,000  (E ints, dst-sorted src ids)
//  rowL : 11,520,000 .. 11,560,000  (N ints, LOCAL exclusive prefix)
//  cnt  : 11,700,000 .. 11,740,000  (N ints, histogram)   | zeroed together
//  cur  : 11,740,000 .. 11,780,000  (N ints, fill cursors) | (one memset)
//  bsum : 11,800,000 .. +157
//  bpre : 11,810,000 .. +157

__device__ __forceinline__ unsigned short f2bf(float f) {
  const unsigned u = __float_as_uint(f);
  return (unsigned short)((u + 0x7FFFu + ((u >> 16) & 1u)) >> 16);  // RNE
}
__device__ __forceinline__ float bflo(unsigned p) {
  return __uint_as_float(p << 16);
}
__device__ __forceinline__ float bfhi(unsigned p) {
  return __uint_as_float(p & 0xFFFF0000u);
}

// MFMA bf16 GEMM: one block = 128 rows x 128 cols, K=128 fully LDS-resident.
// blockIdx.y: 0 = xh=bf16(feat@Wlin) + alpha epilogue (alpha from fp32 D);
//             1 = outp = feat@Wres; 2 = fused dst-histogram.
// Wave w: n-tiles {2w, 2w+1} x all 8 m-tiles. Frag layouts (verified m89/m91/m120):
//   A[m=lane&15][k=quad*8+j], B[k=quad*8+j][n=lane&15], D[row=quad*4+r][col=lane&15].
__global__ __launch_bounds__(256, 2) void k_gemm(
    const float* __restrict__ feat, const float* __restrict__ Wlin,
    const float* __restrict__ Wres, const float* __restrict__ attl,
    const float* __restrict__ attr, unsigned short* __restrict__ xh,
    float* __restrict__ al, float* __restrict__ ar, float* __restrict__ outp,
    const int* __restrict__ dst, int* __restrict__ cnt)
{
  __shared__ float smemf[17408];   // 69,632 B: sA[128][136]bf16 | sB[128][136]bf16 ; reuse: sD[128][132]f32
  const int t = threadIdx.x;

  if (blockIdx.y == 2) {           // fused histogram
    const int stride = NB_GEMM * 256;
    for (int e = blockIdx.x * 256 + t; e < N_EDGES; e += stride)
      atomicAdd(&cnt[dst[e]], 1);
    return;
  }

  short* sA = (short*)smemf;               // [row][KP]
  short* sB = ((short*)smemf) + 17408;     // [n][KP]  (17408 shorts = 34,816 B)
  const int row0 = blockIdx.x * 128;
  const int isRes = blockIdx.y;
  const float* __restrict__ W = isRes ? Wres : Wlin;

  // --- stage A: coalesced float4 row-reads -> bf16 -> sA[row][k] (b64 writes, ~2-way)
  {
    const int kq = t & 31;              // k-quad: k = kq*4
    const int rb = (t >> 5) * 16;       // 16 rows per thread-group
    #pragma unroll
    for (int i = 0; i < 16; ++i) {
      const int r = rb + i;
      const int rr = min(row0 + r, N_NODES - 1);
      const float4 f = *(const float4*)&feat[(long)rr * 128 + kq * 4];
      const unsigned lo = (unsigned)f2bf(f.x) | ((unsigned)f2bf(f.y) << 16);
      const unsigned hi = (unsigned)f2bf(f.z) | ((unsigned)f2bf(f.w) << 16);
      *(uint2*)&sA[r * KP + kq * 4] = make_uint2(lo, hi);
    }
  }
  // --- stage B: coalesced scalar row-reads of W[k][n] -> transposed sB[n][k]
  {
    const int n = t & 127;
    const int kh = (t >> 7) * 64;       // k-half
    #pragma unroll
    for (int j = 0; j < 16; ++j) {
      const int k = kh + j * 4;
      const float w0 = W[(long)(k + 0) * 128 + n];
      const float w1 = W[(long)(k + 1) * 128 + n];
      const float w2 = W[(long)(k + 2) * 128 + n];
      const float w3 = W[(long)(k + 3) * 128 + n];
      const unsigned lo = (unsigned)f2bf(w0) | ((unsigned)f2bf(w1) << 16);
      const unsigned hi = (unsigned)f2bf(w2) | ((unsigned)f2bf(w3) << 16);
      *(uint2*)&sB[n * KP + k] = make_uint2(lo, hi);
    }
  }
  __syncthreads();

  const int w = t >> 6;
  const int lane = t & 63;
  const int c15 = lane & 15, q = lane >> 4;

  floatx4 acc[8][2];
  #pragma unroll
  for (int mt = 0; mt < 8; ++mt)
    #pragma unroll
    for (int nt = 0; nt < 2; ++nt)
      acc[mt][nt] = (floatx4){0.f, 0.f, 0.f, 0.f};

  #pragma unroll
  for (int kc = 0; kc < 4; ++kc) {
    short8 bfr[2];
    #pragma unroll
    for (int nt = 0; nt < 2; ++nt) {
      const int n = (w * 2 + nt) * 16 + c15;
      bfr[nt] = *(const short8*)&sB[n * KP + kc * 32 + q * 8];
    }
    #pragma unroll
    for (int mt = 0; mt < 8; ++mt) {
      const int r = mt * 16 + c15;
      const short8 afr = *(const short8*)&sA[r * KP + kc * 32 + q * 8];
      acc[mt][0] = __builtin_amdgcn_mfma_f32_16x16x32_bf16(afr, bfr[0], acc[mt][0], 0, 0, 0);
      acc[mt][1] = __builtin_amdgcn_mfma_f32_16x16x32_bf16(afr, bfr[1], acc[mt][1], 0, 0, 0);
    }
  }
  __syncthreads();   // sA/sB dead; reuse as sD

  // D -> LDS f32 [128][132] for coalesced stores + alpha (2-way banks, free)
  float* sD = smemf;
  #pragma unroll
  for (int mt = 0; mt < 8; ++mt)
    #pragma unroll
    for (int nt = 0; nt < 2; ++nt) {
      const int col = (w * 2 + nt) * 16 + c15;
      #pragma unroll
      for (int r = 0; r < 4; ++r)
        sD[(mt * 16 + q * 4 + r) * 132 + col] = acc[mt][nt][r];
    }
  __syncthreads();

  const int orow = t >> 1, half = t & 1;
  const int grow = row0 + orow;
  if (isRes) {
    if (grow < N_NODES) {
      #pragma unroll
      for (int i = 0; i < 16; ++i) {
        const float4 v = *(const float4*)&sD[orow * 132 + half * 64 + i * 4];
        *(float4*)&outp[(long)grow * 128 + half * 64 + i * 4] = v;
      }
    }
  } else {
    if (grow < N_NODES) {
      #pragma unroll
      for (int i = 0; i < 8; ++i) {
        const float4 v0 = *(const float4*)&sD[orow * 132 + half * 64 + i * 8];
        const float4 v1 = *(const float4*)&sD[orow * 132 + half * 64 + i * 8 + 4];
        uint4 u;
        u.x = (unsigned)f2bf(v0.x) | ((unsigned)f2bf(v0.y) << 16);
        u.y = (unsigned)f2bf(v0.z) | ((unsigned)f2bf(v0.w) << 16);
        u.z = (unsigned)f2bf(v1.x) | ((unsigned)f2bf(v1.y) << 16);
        u.w = (unsigned)f2bf(v1.z) | ((unsigned)f2bf(v1.w) << 16);
        *(uint4*)&xh[(long)grow * 128 + half * 64 + i * 8] = u;
      }
    }
    // alpha from fp32 D: 1024 (row,head) tasks each for l and r
    #pragma unroll
    for (int it = 0; it < 8; ++it) {
      const int task = t + it * 256;
      const int which = task >> 10;
      const int rem = task & 1023;
      const int rr = rem >> 3, hh = rem & 7;
      const float* att = which ? attr : attl;
      float s = 0.f;
      #pragma unroll
      for (int c = 0; c < 16; c += 4) {
        const float4 xv = *(const float4*)&sD[rr * 132 + hh * 16 + c];
        const float4 av = *(const float4*)&att[hh * 16 + c];
        s += xv.x * av.x + xv.y * av.y + xv.z * av.z + xv.w * av.w;
      }
      const int g2 = row0 + rr;
      if (g2 < N_NODES) (which ? ar : al)[(long)g2 * 8 + hh] = s;
    }
  }
}

__global__ __launch_bounds__(256) void k_scan_local(
    const int* __restrict__ cnt, int* __restrict__ rowL, int* __restrict__ bsum)
{
  __shared__ int sd[256];
  const int t = threadIdx.x;
  const int i = blockIdx.x * 256 + t;
  const int v = (i < N_NODES) ? cnt[i] : 0;
  sd[t] = v;
  __syncthreads();
  #pragma unroll
  for (int off = 1; off < 256; off <<= 1) {
    const int add = (t >= off) ? sd[t - off] : 0;
    __syncthreads();
    sd[t] += add;
    __syncthreads();
  }
  if (i < N_NODES) rowL[i] = sd[t] - v;
  if (t == 255) bsum[blockIdx.x] = sd[255];
}

__global__ __launch_bounds__(256) void k_scan_bsum(
    const int* __restrict__ bsum, int* __restrict__ bpre)
{
  __shared__ int sd[256];
  const int t = threadIdx.x;
  const int v = (t < NB_SCAN) ? bsum[t] : 0;
  sd[t] = v;
  __syncthreads();
  #pragma unroll
  for (int off = 1; off < 256; off <<= 1) {
    const int add = (t >= off) ? sd[t - off] : 0;
    __syncthreads();
    sd[t] += add;
    __syncthreads();
  }
  if (t < NB_SCAN) bpre[t] = sd[t] - v;
}

__global__ __launch_bounds__(256) void k_fill_logit(
    const int* __restrict__ src, const int* __restrict__ dst,
    const float* __restrict__ ew, const float* __restrict__ al,
    const float* __restrict__ ar, const int* __restrict__ rowL,
    const int* __restrict__ bpre, int* __restrict__ cur,
    float* __restrict__ plg, int* __restrict__ psrc)
{
  const int e = blockIdx.x * 256 + threadIdx.x;
  if (e >= N_EDGES) return;
  const int s = src[e], d = dst[e];
  const float w = ew[e];
  const float4 l0 = *(const float4*)&al[(long)s * 8];
  const float4 l1 = *(const float4*)&al[(long)s * 8 + 4];
  const float4 r0 = *(const float4*)&ar[(long)d * 8];
  const float4 r1 = *(const float4*)&ar[(long)d * 8 + 4];
  float lv[8] = {l0.x + r0.x, l0.y + r0.y, l0.z + r0.z, l0.w + r0.w,
                 l1.x + r1.x, l1.y + r1.y, l1.z + r1.z, l1.w + r1.w};
  #pragma unroll
  for (int h = 0; h < 8; ++h) {
    float a = w * lv[h];
    lv[h] = (a >= 0.f) ? a : 0.2f * a;   // leaky_relu(0.2)
  }
  const int p = rowL[d] + bpre[d >> 8] + atomicAdd(&cur[d], 1);
  psrc[p] = s;
  float4* o = (float4*)&plg[(long)p * 8];
  o[0] = make_float4(lv[0], lv[1], lv[2], lv[3]);
  o[1] = make_float4(lv[4], lv[5], lv[6], lv[7]);
}

// One wave per node: softmax via xor-shuffles, x4-unrolled bf16 gather.
__global__ __launch_bounds__(256) void k_node_agg(
    const int* __restrict__ rowL, const int* __restrict__ bpre,
    const int* __restrict__ psrc, const float* __restrict__ plg,
    const unsigned short* __restrict__ xh, float* __restrict__ outp)
{
  const int wave = threadIdx.x >> 6;
  const int lane = threadIdx.x & 63;
  const int d = blockIdx.x * 4 + wave;
  const int start = rowL[d] + bpre[d >> 8];
  const int dn = d + 1;
  const int end = (dn == N_NODES) ? N_EDGES : (rowL[dn] + bpre[dn >> 8]);
  const int deg = end - start;
  if (deg <= 0) return;   // out already holds residual; elu(0)=0

  const float* base = plg + (long)start * 8;
  const int nv = deg * 8;

  float m = -INFINITY;
  for (int v = lane; v < nv; v += 64) m = fmaxf(m, base[v]);
  m = fmaxf(m, __shfl_xor(m, 8));
  m = fmaxf(m, __shfl_xor(m, 16));
  m = fmaxf(m, __shfl_xor(m, 32));   // per-head max (head = lane&7)

  float ssum = 0.f;
  for (int v = lane; v < nv; v += 64) ssum += __expf(base[v] - m);
  ssum += __shfl_xor(ssum, 8);
  ssum += __shfl_xor(ssum, 16);
  ssum += __shfl_xor(ssum, 32);      // per-head denom

  const int h = lane >> 3;
  const float mh = __shfl(m, h);
  const float rs = 1.0f / __shfl(ssum, h);

  const int co = lane * 2;
  float2 a0 = {0.f, 0.f}, a1 = {0.f, 0.f}, a2 = {0.f, 0.f}, a3 = {0.f, 0.f};
  int p = start;
  for (; p + 4 <= end; p += 4) {
    const int s0 = psrc[p + 0], s1 = psrc[p + 1];
    const int s2 = psrc[p + 2], s3 = psrc[p + 3];
    const float e0 = __expf(plg[(long)(p + 0) * 8 + h] - mh);
    const float e1 = __expf(plg[(long)(p + 1) * 8 + h] - mh);
    const float e2 = __expf(plg[(long)(p + 2) * 8 + h] - mh);
    const float e3 = __expf(plg[(long)(p + 3) * 8 + h] - mh);
    const unsigned v0 = *(const unsigned*)&xh[(long)s0 * 128 + co];
    const unsigned v1 = *(const unsigned*)&xh[(long)s1 * 128 + co];
    const unsigned v2 = *(const unsigned*)&xh[(long)s2 * 128 + co];
    const unsigned v3 = *(const unsigned*)&xh[(long)s3 * 128 + co];
    a0.x = fmaf(bflo(v0), e0, a0.x); a0.y = fmaf(bfhi(v0), e0, a0.y);
    a1.x = fmaf(bflo(v1), e1, a1.x); a1.y = fmaf(bfhi(v1), e1, a1.y);
    a2.x = fmaf(bflo(v2), e2, a2.x); a2.y = fmaf(bfhi(v2), e2, a2.y);
    a3.x = fmaf(bflo(v3), e3, a3.x); a3.y = fmaf(bfhi(v3), e3, a3.y);
  }
  for (; p < end; ++p) {
    const int s = psrc[p];
    const float e0 = __expf(plg[(long)p * 8 + h] - mh);
    const unsigned v = *(const unsigned*)&xh[(long)s * 128 + co];
    a0.x = fmaf(bflo(v), e0, a0.x);
    a0.y = fmaf(bfhi(v), e0, a0.y);
  }
  const float ax = ((a0.x + a1.x) + (a2.x + a3.x)) * rs;
  const float ay = ((a0.y + a1.y) + (a2.y + a3.y)) * rs;

  float2 o = *(float2*)&outp[(long)d * 128 + co];
  o.x += (ax > 0.f) ? ax : expm1f(ax);
  o.y += (ay > 0.f) ? ay : expm1f(ay);
  *(float2*)&outp[(long)d * 128 + co] = o;
}

extern "C" void kernel_launch(void* const* d_in, const int* in_sizes, int n_in,
                              void* d_out, int out_size, void* d_ws, size_t ws_size,
                              hipStream_t stream) {
  const float* feat = (const float*)d_in[0];
  const int*   eidx = (const int*)d_in[1];
  const float* ew   = (const float*)d_in[2];
  const float* Wlin = (const float*)d_in[3];
  const float* attl = (const float*)d_in[4];
  const float* attr = (const float*)d_in[5];
  const float* Wres = (const float*)d_in[6];
  float* outp = (float*)d_out;

  float* ws = (float*)d_ws;
  unsigned short* xh = (unsigned short*)ws;
  float* al   = ws + 5120000;
  float* ar   = ws + 5440000;
  float* plg  = ws + 5760000;
  int*   psrc = (int*)(ws + 10880000);
  int*   rowL = (int*)(ws + 11520000);
  int*   cnt  = (int*)(ws + 11700000);
  int*   cur  = (int*)(ws + 11740000);   // adjacent to cnt: one memset
  int*   bsum = (int*)(ws + 11800000);
  int*   bpre = (int*)(ws + 11810000);

  const int* src = eidx;
  const int* dst = eidx + N_EDGES;

  hipMemsetAsync(cnt, 0, (size_t)2 * N_NODES * 4, stream);  // cnt + cur

  dim3 ggrid(NB_GEMM, 3);  // y=0 lin, y=1 res, y=2 histogram
  k_gemm<<<ggrid, 256, 0, stream>>>(feat, Wlin, Wres, attl, attr, xh, al, ar,
                                    outp, dst, cnt);
  k_scan_local<<<NB_SCAN, 256, 0, stream>>>(cnt, rowL, bsum);
  k_scan_bsum<<<1, 256, 0, stream>>>(bsum, bpre);
  k_fill_logit<<<(N_EDGES + 255) / 256, 256, 0, stream>>>(src, dst, ew, al, ar,
                                                          rowL, bpre, cur, plg, psrc);
  k_node_agg<<<N_NODES / 4, 256, 0, stream>>>(rowL, bpre, psrc, plg, xh, outp);
}